// Round 1
// 320.969 us; speedup vs baseline: 1.0714x; 1.0714x over previous
//
#include <hip/hip_runtime.h>
#include <hip/hip_bf16.h>
#include <stdint.h>

#define BB 4
#define SS 2048
#define HH 1024
#define NHH 16
#define HDD 64
#define M_TOT (BB*SS)          // 8192

// workspace layout (ushort/bf16 element offsets)
#define XB_OFF 0                              // hidden bf16 [8192][1024]
#define WT_OFF (M_TOT*HH)                     // Wq^T,Wk^T,Wv^T bf16 [3][N=1024][K=1024]
#define Q_OFF  (WT_OFF + 3*HH*HH)             // Q  [B][NH][S][HD]  (pre-scaled by 0.125*log2e!)
#define K_OFF  (Q_OFF + BB*NHH*SS*HDD)        // K  [B][NH][S][HD]
#define VT_OFF (K_OFF + BB*NHH*SS*HDD)        // Vt [B][NH][HD][S]  (transposed)

typedef short bf16x8 __attribute__((ext_vector_type(8)));
typedef float f32x4  __attribute__((ext_vector_type(4)));

__device__ inline unsigned short f2bf(float f){
  unsigned u = __float_as_uint(f);
  u += 0x7fffu + ((u >> 16) & 1u);   // RNE
  return (unsigned short)(u >> 16);
}
__device__ inline unsigned pk2bf(float lo, float hi){
  float2 t; t.x = lo; t.y = hi;
  __hip_bfloat162 h = __float22bfloat162_rn(t);
  return *(unsigned*)&h;
}

// async global->LDS, 16B per lane
__device__ __forceinline__ void ld_g2l_16(const unsigned short* g, unsigned short* l){
  __builtin_amdgcn_global_load_lds(
      (const __attribute__((address_space(1))) void*)g,
      (__attribute__((address_space(3))) void*)l, 16, 0, 0);
}

// ---------------- kernel 1a: X fp32 -> bf16 ----------------
__global__ void convert_x(const float* __restrict__ hs, unsigned short* __restrict__ xb){
  const int i = blockIdx.x*blockDim.x + threadIdx.x;
  float4 v = ((const float4*)hs)[i];
  ushort4 o;
  o.x = f2bf(v.x); o.y = f2bf(v.y); o.z = f2bf(v.z); o.w = f2bf(v.w);
  ((ushort4*)xb)[i] = o;
}

// ---------------- kernel 1b: W [K][N] fp32 -> WT [N][K] bf16 ----------------
__global__ void convert_wt(const float* __restrict__ wq, const float* __restrict__ wk,
                           const float* __restrict__ wv, unsigned short* __restrict__ wt){
  __shared__ unsigned short t[64][65];
  const int z = blockIdx.z;
  const float* W = (z==0) ? wq : ((z==1) ? wk : wv);
  unsigned short* WT = wt + z*HH*HH;
  const int kb = blockIdx.x*64, nb = blockIdx.y*64;
  const int tid = threadIdx.x;
  #pragma unroll
  for (int i = 0; i < 16; i++){
    const int idx = i*256 + tid;
    const int r = idx >> 6, c = idx & 63;
    t[r][c] = f2bf(W[(kb + r)*HH + nb + c]);
  }
  __syncthreads();
  #pragma unroll
  for (int i = 0; i < 16; i++){
    const int idx = i*256 + tid;
    const int n = idx >> 6, k = idx & 63;
    WT[(nb + n)*HH + kb + k] = t[k][n];
  }
}

// ---------------- kernel 2: QKV projection GEMM (m97 structure) ----------------
// z==0 (Q) output is pre-scaled by 0.125*log2e so attention needs no per-score fma.
__global__ __launch_bounds__(256) void qkv_gemm(
    const unsigned short* __restrict__ ws16, unsigned short* __restrict__ wsq,
    const float* __restrict__ bq, const float* __restrict__ bk, const float* __restrict__ bv,
    const float* __restrict__ qe, const float* __restrict__ ke, const float* __restrict__ ve,
    const int* __restrict__ idxp){
  __shared__ unsigned short al[128*32];
  __shared__ unsigned short bl[128*32];

  const unsigned short* Xb = ws16 + XB_OFF;
  const int z = blockIdx.z;
  const unsigned short* Wt = ws16 + WT_OFF + z*HH*HH;
  const float* bias = (z==0) ? bq : ((z==1) ? bk : bv);
  const float* emb  = (z==0) ? qe : ((z==1) ? ke : ve);

  const int tid  = threadIdx.x;
  const int wv   = tid >> 6;
  const int ln   = tid & 63;
  const int quad = ln >> 4;
  const int l15  = ln & 15;
  const int m0 = blockIdx.x * 128;
  const int n0 = blockIdx.y * 128;
  const int wm = wv & 1, wn = wv >> 1;

  const int sr0 = wv*32 + (ln >> 2);
  const int sr1 = sr0 + 16;
  const int sk  = (ln & 3)*8;
  const unsigned short* ga0 = &Xb[(size_t)(m0 + sr0)*HH + sk];
  const unsigned short* ga1 = &Xb[(size_t)(m0 + sr1)*HH + sk];
  const unsigned short* gb0 = &Wt[(size_t)(n0 + sr0)*HH + sk];
  const unsigned short* gb1 = &Wt[(size_t)(n0 + sr1)*HH + sk];
  unsigned short* alb0 = &al[wv*1024];
  unsigned short* alb1 = &al[wv*1024 + 512];
  unsigned short* blb0 = &bl[wv*1024];
  unsigned short* blb1 = &bl[wv*1024 + 512];

  f32x4 acc[4][4] = {};

  for (int k0 = 0; k0 < HH; k0 += 32){
    __syncthreads();
    ld_g2l_16(ga0 + k0, alb0);
    ld_g2l_16(ga1 + k0, alb1);
    ld_g2l_16(gb0 + k0, blb0);
    ld_g2l_16(gb1 + k0, blb1);
    __syncthreads();

    bf16x8 af[4], bf[4];
    #pragma unroll
    for (int i = 0; i < 4; i++){
      af[i] = *(const bf16x8*)&al[(wm*64 + i*16 + l15)*32 + quad*8];
      bf[i] = *(const bf16x8*)&bl[(wn*64 + i*16 + l15)*32 + quad*8];
    }
    #pragma unroll
    for (int mi = 0; mi < 4; mi++)
      #pragma unroll
      for (int ni = 0; ni < 4; ni++)
        acc[mi][ni] = __builtin_amdgcn_mfma_f32_16x16x32_bf16(af[mi], bf[ni], acc[mi][ni], 0, 0, 0);
  }

  const int index = idxp[0];
  const float oscale = (z==0) ? 0.18033688011112042f : 1.0f;  // 0.125*log2(e) for Q
  #pragma unroll
  for (int ni = 0; ni < 4; ni++){
    const int n = n0 + wn*64 + ni*16 + l15;
    const float biasv = bias[n] + emb[index*HH + n];
    const int h = n >> 6, d = n & 63;
    #pragma unroll
    for (int mi = 0; mi < 4; mi++){
      #pragma unroll
      for (int r = 0; r < 4; r++){
        const int g  = m0 + wm*64 + mi*16 + quad*4 + r;
        const int b_ = g >> 11;
        const int s_ = g & (SS - 1);
        const int bh = b_*NHH + h;
        const unsigned short val = f2bf((acc[mi][ni][r] + biasv) * oscale);
        if (z == 2)      wsq[VT_OFF + (size_t)(bh*HDD + d)*SS + s_] = val;
        else if (z == 0) wsq[Q_OFF  + (size_t)(bh*SS + s_)*HDD + d] = val;
        else             wsq[K_OFF  + (size_t)(bh*SS + s_)*HDD + d] = val;
      }
    }
  }
}

// ---------------- kernel 3: flash attention, q-split waves ----------------
// Block = 128 q rows of one (b,h); wave w owns q in [w*32,(w+1)*32), iterates ALL
// 2048 kt in 64 chunks of 32. K/V^T staged per-chunk into double-buffered LDS via
// global_load_lds (T3-minimal prefetch: stage(ch+1) issued before compute(ch), one
// barrier/chunk). K LDS tile is XOR-swizzled via pre-swizzled global SOURCE (rule 21)
// so ds_read_b128 at 128B row stride is conflict-free; V^T rows are 64B (no conflict).
// Fixed-max softmax: Q pre-scaled by 0.125*log2e, mask*log2e enters as MFMA C-init.
// Grid = 1024 blocks, 26.6KB LDS, <=128 VGPR -> 4 blocks/CU, ALL blocks resident.
#define ST_P 40   // P^T row stride (shorts): 80B (2-way max on write, ~uniform on read)
__global__ __launch_bounds__(256, 4) void attn_mfma(
    const unsigned short* __restrict__ ws16,
    const float* __restrict__ mask, float* __restrict__ out){
  __shared__ __align__(16) unsigned short kb[2][32*64];   // [kt][d], swizzled, 2x4KB
  __shared__ __align__(16) unsigned short vb[2][64*32];   // [d][kt], linear,   2x4KB
  __shared__ __align__(16) unsigned short pb[4][32*ST_P]; // per-wave P^T [q][kt], 10KB

  const int tid  = threadIdx.x;
  const int wave = tid >> 6;
  const int lane = tid & 63;
  const int quad = lane >> 4;
  const int l15  = lane & 15;
  const int qb   = blockIdx.x & 15;          // 16 q-blocks of 128 rows per bh
  const int bh   = blockIdx.x >> 4;
  const int b    = bh >> 4, h = bh & 15;
  const int q0   = qb*128 + wave*32;         // this wave's first q row
  const float LOG2E = 1.4426950408889634f;

  const unsigned short* Qg = ws16 + Q_OFF  + (size_t)bh*SS*HDD;
  const unsigned short* Kg = ws16 + K_OFF  + (size_t)bh*SS*HDD;
  const unsigned short* Vg = ws16 + VT_OFF + (size_t)bh*HDD*SS;
  const float* maskB = mask + b*SS;

  // resident Q fragments: B-operand (n=q=qg*16+l15, k=d=h2*32+quad*8+j)
  bf16x8 aq[2][2];
  #pragma unroll
  for (int qg = 0; qg < 2; qg++)
    #pragma unroll
    for (int h2 = 0; h2 < 2; h2++)
      aq[qg][h2] = *(const bf16x8*)(Qg + (size_t)(q0 + qg*16 + l15)*HDD + h2*32 + quad*8);

  // staging sources (per-thread). K source col is pre-XOR-swizzled so the linear
  // global_load_lds dest yields LDS[kt][col ^ ((kt&7)<<4)].
  const int kr = tid >> 3, kp = tid & 7;     // K tile: 32 rows x 128B, 8 pieces/row
  const int vr = tid >> 2, vp = tid & 3;     // V tile: 64 rows x  64B, 4 pieces/row
  const unsigned short* kSrc = Kg + (size_t)kr*HDD + ((((kp*16) ^ ((kr&7)<<4)))>>1);
  const unsigned short* vSrc = Vg + (size_t)vr*SS + vp*8;
  unsigned short* kDst = &kb[0][0] + (tid>>6)*512;   // wave-uniform base (+lane*16B)
  unsigned short* vDst = &vb[0][0] + (tid>>6)*512;
  unsigned short* pw   = &pb[wave][0];

  f32x4 O[4][2] = {};            // O^T: elem (d=dg*16+quad*4+r, q=qg*16+l15)
  float lacc[2] = {0.f, 0.f};

  // prologue: stage chunk 0 into buffer 0 (syncthreads drains vmcnt)
  ld_g2l_16(kSrc, kDst);
  ld_g2l_16(vSrc, vDst);
  __syncthreads();

  #pragma unroll 2
  for (int ch = 0; ch < 64; ++ch){
    const int cur = ch & 1;
    const int ktb = ch*32;
    if (ch < 63){                // issue next-chunk stage BEFORE compute (overlap)
      ld_g2l_16(kSrc + (size_t)(ktb + 32)*HDD, kDst + (cur^1)*2048);
      ld_g2l_16(vSrc + (ktb + 32),             vDst + (cur^1)*2048);
    }
    const unsigned short* kcur = &kb[cur][0];
    const unsigned short* vcur = &vb[cur][0];

    // K fragments: A-operand (m=kt=fi*16+l15, k=d), swizzled read
    bf16x8 ka[2][2];
    #pragma unroll
    for (int fi = 0; fi < 2; fi++)
      #pragma unroll
      for (int h2 = 0; h2 < 2; h2++){
        const int colb = (h2*64 + quad*16) ^ ((l15 & 7) << 4);
        ka[fi][h2] = *(const bf16x8*)&kcur[(fi*16 + l15)*64 + (colb>>1)];
      }

    // S^T = K·Q^T with C init = mask*log2e -> p = exp2(st) -> P^T to LDS
    #pragma unroll
    for (int fi = 0; fi < 2; fi++){
      const float4 mr = *(const float4*)(maskB + ktb + fi*16 + quad*4);
      f32x4 mv; mv[0]=mr.x*LOG2E; mv[1]=mr.y*LOG2E; mv[2]=mr.z*LOG2E; mv[3]=mr.w*LOG2E;
      #pragma unroll
      for (int qg = 0; qg < 2; qg++){
        f32x4 st = mv;
        st = __builtin_amdgcn_mfma_f32_16x16x32_bf16(ka[fi][0], aq[qg][0], st, 0,0,0);
        st = __builtin_amdgcn_mfma_f32_16x16x32_bf16(ka[fi][1], aq[qg][1], st, 0,0,0);
        f32x4 p;
        #pragma unroll
        for (int r = 0; r < 4; r++) p[r] = exp2f(st[r]);
        lacc[qg] += (p[0] + p[1]) + (p[2] + p[3]);
        uint2 w; w.x = pk2bf(p[0], p[1]); w.y = pk2bf(p[2], p[3]);
        *(uint2*)&pw[(qg*16 + l15)*ST_P + fi*16 + quad*4] = w;
      }
    }

    // V^T fragments: A-operand (m=d=dg*16+l15, k=kt=quad*8+j), 64B rows (no conflict)
    bf16x8 va[4];
    #pragma unroll
    for (int dg = 0; dg < 4; dg++)
      va[dg] = *(const bf16x8*)&vcur[(dg*16 + l15)*32 + quad*8];

    // O^T += V^T · P^T  (intra-wave LDS round-trip, wave-ordered, no barrier)
    #pragma unroll
    for (int qg = 0; qg < 2; qg++){
      bf16x8 bp = *(const bf16x8*)&pw[(qg*16 + l15)*ST_P + quad*8];
      #pragma unroll
      for (int dg = 0; dg < 4; dg++)
        O[dg][qg] = __builtin_amdgcn_mfma_f32_16x16x32_bf16(va[dg], bp, O[dg][qg], 0,0,0);
    }

    __syncthreads();   // waves done reading cur; next-chunk stage (cur^1) drained
  }

  // row sums: reduce lacc across quads (lanes with same l15 share q)
  float inv[2];
  #pragma unroll
  for (int qg = 0; qg < 2; qg++){
    float lq = lacc[qg];
    lq += __shfl_xor(lq, 16);
    lq += __shfl_xor(lq, 32);
    inv[qg] = 1.0f / lq;
  }

  // epilogue: scale by 1/l, write ctx [B,S,H] fp32 as float4 per (dg,qg)
  #pragma unroll
  for (int qg = 0; qg < 2; qg++){
    float* op = out + ((size_t)b*SS + q0 + qg*16 + l15)*HH + h*HDD + quad*4;
    #pragma unroll
    for (int dg = 0; dg < 4; dg++){
      f32x4 v = O[dg][qg];
      float4 o; o.x = v[0]*inv[qg]; o.y = v[1]*inv[qg]; o.z = v[2]*inv[qg]; o.w = v[3]*inv[qg];
      *(float4*)(op + dg*16) = o;
    }
  }
}

extern "C" void kernel_launch(void* const* d_in, const int* in_sizes, int n_in,
                              void* d_out, int out_size, void* d_ws, size_t ws_size,
                              hipStream_t stream){
  const float* hs   = (const float*)d_in[0];
  const float* mask = (const float*)d_in[1];
  const float* Wq   = (const float*)d_in[2];
  const float* bq   = (const float*)d_in[3];
  const float* Wk   = (const float*)d_in[4];
  const float* bk   = (const float*)d_in[5];
  const float* Wv   = (const float*)d_in[6];
  const float* bv   = (const float*)d_in[7];
  const float* qe   = (const float*)d_in[8];
  const float* ke   = (const float*)d_in[9];
  const float* ve   = (const float*)d_in[10];
  const int*   idx  = (const int*)d_in[11];
  unsigned short* ws16 = (unsigned short*)d_ws;
  float* out = (float*)d_out;

  convert_x<<<M_TOT*HH/4/256, 256, 0, stream>>>(hs, ws16 + XB_OFF);
  dim3 gt(HH/64, HH/64, 3);
  convert_wt<<<gt, 256, 0, stream>>>(Wq, Wk, Wv, ws16 + WT_OFF);

  dim3 g2(M_TOT/128, HH/128, 3);
  qkv_gemm<<<g2, 256, 0, stream>>>(ws16, ws16, bq, bk, bv, qe, ke, ve, idx);

  attn_mfma<<<BB*NHH*SS/128, 256, 0, stream>>>(ws16, mask, out);
}

// Round 2
// 292.646 us; speedup vs baseline: 1.1750x; 1.0968x over previous
//
#include <hip/hip_runtime.h>
#include <hip/hip_bf16.h>
#include <stdint.h>

#define BB 4
#define SS 2048
#define HH 1024
#define NHH 16
#define HDD 64
#define M_TOT (BB*SS)          // 8192

// workspace layout (ushort/bf16 element offsets)
#define XB_OFF 0                              // hidden bf16 [8192][1024]
#define WT_OFF (M_TOT*HH)                     // Wq^T,Wk^T,Wv^T bf16 [3][N=1024][K=1024]
#define Q_OFF  (WT_OFF + 3*HH*HH)             // Q  [B][NH][S][HD]  (pre-scaled by 0.125*log2e!)
#define K_OFF  (Q_OFF + BB*NHH*SS*HDD)        // K  [B][NH][S][HD]
#define VT_OFF (K_OFF + BB*NHH*SS*HDD)        // Vt [B][NH][HD][S]  (transposed)

typedef short bf16x8 __attribute__((ext_vector_type(8)));
typedef float f32x4  __attribute__((ext_vector_type(4)));

__device__ inline unsigned short f2bf(float f){
  unsigned u = __float_as_uint(f);
  u += 0x7fffu + ((u >> 16) & 1u);   // RNE
  return (unsigned short)(u >> 16);
}
__device__ inline unsigned pk2bf(float lo, float hi){
  float2 t; t.x = lo; t.y = hi;
  __hip_bfloat162 h = __float22bfloat162_rn(t);
  return *(unsigned*)&h;
}

// async global->LDS, 16B per lane
__device__ __forceinline__ void ld_g2l_16(const unsigned short* g, unsigned short* l){
  __builtin_amdgcn_global_load_lds(
      (const __attribute__((address_space(1))) void*)g,
      (__attribute__((address_space(3))) void*)l, 16, 0, 0);
}

// ---------------- kernel 1a: X fp32 -> bf16 ----------------
__global__ void convert_x(const float* __restrict__ hs, unsigned short* __restrict__ xb){
  const int i = blockIdx.x*blockDim.x + threadIdx.x;
  float4 v = ((const float4*)hs)[i];
  ushort4 o;
  o.x = f2bf(v.x); o.y = f2bf(v.y); o.z = f2bf(v.z); o.w = f2bf(v.w);
  ((ushort4*)xb)[i] = o;
}

// ---------------- kernel 1b: W [K][N] fp32 -> WT [N][K] bf16 ----------------
__global__ void convert_wt(const float* __restrict__ wq, const float* __restrict__ wk,
                           const float* __restrict__ wv, unsigned short* __restrict__ wt){
  __shared__ unsigned short t[64][65];
  const int z = blockIdx.z;
  const float* W = (z==0) ? wq : ((z==1) ? wk : wv);
  unsigned short* WT = wt + z*HH*HH;
  const int kb = blockIdx.x*64, nb = blockIdx.y*64;
  const int tid = threadIdx.x;
  #pragma unroll
  for (int i = 0; i < 16; i++){
    const int idx = i*256 + tid;
    const int r = idx >> 6, c = idx & 63;
    t[r][c] = f2bf(W[(kb + r)*HH + nb + c]);
  }
  __syncthreads();
  #pragma unroll
  for (int i = 0; i < 16; i++){
    const int idx = i*256 + tid;
    const int n = idx >> 6, k = idx & 63;
    WT[(nb + n)*HH + kb + k] = t[k][n];
  }
}

// ---------------- kernel 2: QKV projection GEMM (m97 structure) ----------------
// z==0 (Q) output is pre-scaled by 0.125*log2e so attention needs no per-score fma.
__global__ __launch_bounds__(256) void qkv_gemm(
    const unsigned short* __restrict__ ws16, unsigned short* __restrict__ wsq,
    const float* __restrict__ bq, const float* __restrict__ bk, const float* __restrict__ bv,
    const float* __restrict__ qe, const float* __restrict__ ke, const float* __restrict__ ve,
    const int* __restrict__ idxp){
  __shared__ unsigned short al[128*32];
  __shared__ unsigned short bl[128*32];

  const unsigned short* Xb = ws16 + XB_OFF;
  const int z = blockIdx.z;
  const unsigned short* Wt = ws16 + WT_OFF + z*HH*HH;
  const float* bias = (z==0) ? bq : ((z==1) ? bk : bv);
  const float* emb  = (z==0) ? qe : ((z==1) ? ke : ve);

  const int tid  = threadIdx.x;
  const int wv   = tid >> 6;
  const int ln   = tid & 63;
  const int quad = ln >> 4;
  const int l15  = ln & 15;
  const int m0 = blockIdx.x * 128;
  const int n0 = blockIdx.y * 128;
  const int wm = wv & 1, wn = wv >> 1;

  const int sr0 = wv*32 + (ln >> 2);
  const int sr1 = sr0 + 16;
  const int sk  = (ln & 3)*8;
  const unsigned short* ga0 = &Xb[(size_t)(m0 + sr0)*HH + sk];
  const unsigned short* ga1 = &Xb[(size_t)(m0 + sr1)*HH + sk];
  const unsigned short* gb0 = &Wt[(size_t)(n0 + sr0)*HH + sk];
  const unsigned short* gb1 = &Wt[(size_t)(n0 + sr1)*HH + sk];
  unsigned short* alb0 = &al[wv*1024];
  unsigned short* alb1 = &al[wv*1024 + 512];
  unsigned short* blb0 = &bl[wv*1024];
  unsigned short* blb1 = &bl[wv*1024 + 512];

  f32x4 acc[4][4] = {};

  for (int k0 = 0; k0 < HH; k0 += 32){
    __syncthreads();
    ld_g2l_16(ga0 + k0, alb0);
    ld_g2l_16(ga1 + k0, alb1);
    ld_g2l_16(gb0 + k0, blb0);
    ld_g2l_16(gb1 + k0, blb1);
    __syncthreads();

    bf16x8 af[4], bf[4];
    #pragma unroll
    for (int i = 0; i < 4; i++){
      af[i] = *(const bf16x8*)&al[(wm*64 + i*16 + l15)*32 + quad*8];
      bf[i] = *(const bf16x8*)&bl[(wn*64 + i*16 + l15)*32 + quad*8];
    }
    #pragma unroll
    for (int mi = 0; mi < 4; mi++)
      #pragma unroll
      for (int ni = 0; ni < 4; ni++)
        acc[mi][ni] = __builtin_amdgcn_mfma_f32_16x16x32_bf16(af[mi], bf[ni], acc[mi][ni], 0, 0, 0);
  }

  const int index = idxp[0];
  const float oscale = (z==0) ? 0.18033688011112042f : 1.0f;  // 0.125*log2(e) for Q
  #pragma unroll
  for (int ni = 0; ni < 4; ni++){
    const int n = n0 + wn*64 + ni*16 + l15;
    const float biasv = bias[n] + emb[index*HH + n];
    const int h = n >> 6, d = n & 63;
    #pragma unroll
    for (int mi = 0; mi < 4; mi++){
      #pragma unroll
      for (int r = 0; r < 4; r++){
        const int g  = m0 + wm*64 + mi*16 + quad*4 + r;
        const int b_ = g >> 11;
        const int s_ = g & (SS - 1);
        const int bh = b_*NHH + h;
        const unsigned short val = f2bf((acc[mi][ni][r] + biasv) * oscale);
        if (z == 2)      wsq[VT_OFF + (size_t)(bh*HDD + d)*SS + s_] = val;
        else if (z == 0) wsq[Q_OFF  + (size_t)(bh*SS + s_)*HDD + d] = val;
        else             wsq[K_OFF  + (size_t)(bh*SS + s_)*HDD + d] = val;
      }
    }
  }
}

// ---------------- kernel 3: flash attention, 16q/wave, 8-wave blocks ----------------
// Block = 512 threads (8 waves) covering 128 q rows of one (b,h); wave w owns q rows
// [w*16,(w+1)*16). 8192 total waves -> 8 waves/SIMD available (was 4). K/V staged
// per 32-kt chunk into double-buffered LDS: waves 0-3 stage K, waves 4-7 stage V
// (1 global_load_lds per thread per chunk). K LDS is XOR-swizzled via pre-swizzled
// global SOURCE (rule 21) -> conflict-free ds_read_b128; V^T rows 64B linear.
// mask*log2e staged to LDS once per block. Native exp2. Fixed-max softmax (Q
// pre-scaled by 0.125*log2e; mask enters as MFMA C-init).
// XCD swizzle: all 16 blocks of one (b,h) pinned to one XCD -> K/V fetched once.
// LDS 34.8KB -> 4 blocks/CU; grid 1024 = 4 blocks/CU -> up to 8 waves/SIMD.
#define ST_P 40   // P^T row stride (shorts): 80B
__global__ __launch_bounds__(512, 6) void attn_mfma(
    const unsigned short* __restrict__ ws16,
    const float* __restrict__ mask, float* __restrict__ out){
  __shared__ __align__(16) unsigned short kb[2][32*64];   // [kt][d], swizzled, 2x4KB
  __shared__ __align__(16) unsigned short vb[2][64*32];   // [d][kt], linear,   2x4KB
  __shared__ __align__(16) unsigned short pb[8][16*ST_P]; // per-wave P^T [q][kt], 10.24KB
  __shared__ __align__(16) float mlds[SS];                // mask row * log2e, 8KB

  const int tid  = threadIdx.x;
  const int wave = tid >> 6;
  const int lane = tid & 63;
  const int quad = lane >> 4;
  const int l15  = lane & 15;

  // XCD-aware swizzle (bijective: 1024 % 8 == 0): XCD x gets logical [x*128,(x+1)*128)
  // = 8 complete (b,h) -> each head's K/V stream served by a single XCD's L2.
  const int bid  = (blockIdx.x & 7)*128 + (blockIdx.x >> 3);
  const int qb   = bid & 15;                 // 16 q-blocks of 128 rows per bh
  const int bh   = bid >> 4;
  const int b    = bh >> 4, h = bh & 15;
  const int q0   = qb*128 + wave*16;         // this wave's first q row
  const float LOG2E = 1.4426950408889634f;

  const unsigned short* Qg = ws16 + Q_OFF  + (size_t)bh*SS*HDD;
  const unsigned short* Kg = ws16 + K_OFF  + (size_t)bh*SS*HDD;
  const unsigned short* Vg = ws16 + VT_OFF + (size_t)bh*HDD*SS;
  const float* maskB = mask + b*SS;

  // stage mask row * log2e (512 threads x float4 = 8KB)
  {
    float4 m4 = ((const float4*)maskB)[tid];
    m4.x*=LOG2E; m4.y*=LOG2E; m4.z*=LOG2E; m4.w*=LOG2E;
    *(float4*)&mlds[tid*4] = m4;
  }

  // resident Q fragments: B-operand (n=q=l15, k=d=h2*32+quad*8+j)
  bf16x8 aq[2];
  #pragma unroll
  for (int h2 = 0; h2 < 2; h2++)
    aq[h2] = *(const bf16x8*)(Qg + (size_t)(q0 + l15)*HDD + h2*32 + quad*8);

  // staging role split: waves 0-3 stage K (32 rows x 128B), waves 4-7 stage V (64 x 64B).
  // K source col pre-XOR-swizzled so linear dest yields LDS[kt][col ^ ((kt&7)<<4)].
  const unsigned short* sSrc;
  unsigned short* sDst;
  int sAdv;
  if (tid < 256){
    const int kr = tid >> 3, kp = tid & 7;
    sSrc = Kg + (size_t)kr*HDD + ((((kp*16) ^ ((kr&7)<<4)))>>1);
    sDst = &kb[0][0] + tid*8;                // 16B per thread, linear
    sAdv = 32*HDD;                           // next 32 kt rows
  } else {
    const int t = tid - 256;
    const int vr = t >> 2, vp = t & 3;
    sSrc = Vg + (size_t)vr*SS + vp*8;
    sDst = &vb[0][0] + t*8;
    sAdv = 32;                               // next 32 kt cols
  }
  unsigned short* pw = &pb[wave][0];

  f32x4 O[4] = {};               // O^T: elem (d=dg*16+quad*4+r, q=l15)
  float lacc = 0.f;

  // prologue: stage chunk 0 into buffer 0 (syncthreads drains vmcnt)
  ld_g2l_16(sSrc, sDst);
  const unsigned short* sp = sSrc + sAdv;
  __syncthreads();

  #pragma unroll 2
  for (int ch = 0; ch < 64; ++ch){
    const int cur = ch & 1;
    const int ktb = ch*32;
    if (ch < 63){                // issue next-chunk stage BEFORE compute (overlap)
      ld_g2l_16(sp, sDst + (cur^1)*2048);
      sp += sAdv;
    }
    const unsigned short* kcur = &kb[cur][0];
    const unsigned short* vcur = &vb[cur][0];

    // K fragments: A-operand (m=kt=fi*16+l15, k=d), swizzled read (conflict-free)
    bf16x8 ka[2][2];
    #pragma unroll
    for (int fi = 0; fi < 2; fi++)
      #pragma unroll
      for (int h2 = 0; h2 < 2; h2++){
        const int colb = (h2*64 + quad*16) ^ ((l15 & 7) << 4);
        ka[fi][h2] = *(const bf16x8*)&kcur[(fi*16 + l15)*64 + (colb>>1)];
      }

    // S^T = K·Q^T with C init = mask*log2e -> p = exp2(st) -> P^T to LDS
    #pragma unroll
    for (int fi = 0; fi < 2; fi++){
      f32x4 st = *(const f32x4*)&mlds[ktb + fi*16 + quad*4];  // same-addr broadcast
      st = __builtin_amdgcn_mfma_f32_16x16x32_bf16(ka[fi][0], aq[0], st, 0,0,0);
      st = __builtin_amdgcn_mfma_f32_16x16x32_bf16(ka[fi][1], aq[1], st, 0,0,0);
      f32x4 p;
      #pragma unroll
      for (int r = 0; r < 4; r++) p[r] = __builtin_amdgcn_exp2f(st[r]);
      lacc += (p[0] + p[1]) + (p[2] + p[3]);
      uint2 w; w.x = pk2bf(p[0], p[1]); w.y = pk2bf(p[2], p[3]);
      *(uint2*)&pw[l15*ST_P + fi*16 + quad*4] = w;
    }

    // V^T fragments: A-operand (m=d=dg*16+l15, k=kt=quad*8+j), 64B rows
    bf16x8 va[4];
    #pragma unroll
    for (int dg = 0; dg < 4; dg++)
      va[dg] = *(const bf16x8*)&vcur[(dg*16 + l15)*32 + quad*8];

    // O^T += V^T · P^T  (intra-wave LDS round-trip, wave-ordered, no barrier)
    {
      bf16x8 bp = *(const bf16x8*)&pw[l15*ST_P + quad*8];
      #pragma unroll
      for (int dg = 0; dg < 4; dg++)
        O[dg] = __builtin_amdgcn_mfma_f32_16x16x32_bf16(va[dg], bp, O[dg], 0,0,0);
    }

    __syncthreads();   // all waves done reading cur; next-chunk stage drained
  }

  // row sum: reduce lacc across quads (lanes with same l15 share q)
  float lq = lacc;
  lq += __shfl_xor(lq, 16);
  lq += __shfl_xor(lq, 32);
  const float inv = 1.0f / lq;

  // epilogue: scale by 1/l, write ctx [B,S,H] fp32 as float4 per dg
  float* op = out + ((size_t)b*SS + q0 + l15)*HH + h*HDD + quad*4;
  #pragma unroll
  for (int dg = 0; dg < 4; dg++){
    f32x4 v = O[dg];
    float4 o; o.x = v[0]*inv; o.y = v[1]*inv; o.z = v[2]*inv; o.w = v[3]*inv;
    *(float4*)(op + dg*16) = o;
  }
}

extern "C" void kernel_launch(void* const* d_in, const int* in_sizes, int n_in,
                              void* d_out, int out_size, void* d_ws, size_t ws_size,
                              hipStream_t stream){
  const float* hs   = (const float*)d_in[0];
  const float* mask = (const float*)d_in[1];
  const float* Wq   = (const float*)d_in[2];
  const float* bq   = (const float*)d_in[3];
  const float* Wk   = (const float*)d_in[4];
  const float* bk   = (const float*)d_in[5];
  const float* Wv   = (const float*)d_in[6];
  const float* bv   = (const float*)d_in[7];
  const float* qe   = (const float*)d_in[8];
  const float* ke   = (const float*)d_in[9];
  const float* ve   = (const float*)d_in[10];
  const int*   idx  = (const int*)d_in[11];
  unsigned short* ws16 = (unsigned short*)d_ws;
  float* out = (float*)d_out;

  convert_x<<<M_TOT*HH/4/256, 256, 0, stream>>>(hs, ws16 + XB_OFF);
  dim3 gt(HH/64, HH/64, 3);
  convert_wt<<<gt, 256, 0, stream>>>(Wq, Wk, Wv, ws16 + WT_OFF);

  dim3 g2(M_TOT/128, HH/128, 3);
  qkv_gemm<<<g2, 256, 0, stream>>>(ws16, ws16, bq, bk, bv, qe, ke, ve, idx);

  attn_mfma<<<BB*NHH*SS/128, 512, 0, stream>>>(ws16, mask, out);
}